// Round 12
// baseline (727.358 us; speedup 1.0000x reference)
//
#include <hip/hip_runtime.h>
#include <math.h>

#define NPT 2048
#define CH 64
constexpr int TDEG = 13;        // Taylor degree for exp(L/16)
constexpr float SCL = 16.0f;    // scaling denominator

// Storage convention: matrix plane-pairs are (h, l2), value = h + l2/2.
// 2-term squaring computes S' = Uh*Uh^T + Uh*Ul2^T whose error vs sym(U)^2 is
// ANTISYMMETRIC; intermediate squarings stay unfixed, one symmetrize-fix per
// consumed output (E05, E2, E8).

typedef __bf16 bf16_t;
typedef __bf16 bf16x8 __attribute__((ext_vector_type(8)));
typedef __bf16 bf16x4_t __attribute__((ext_vector_type(4)));
typedef float f32x4 __attribute__((ext_vector_type(4)));

__device__ __forceinline__ void gl_lds16(const void* g, void* l) {
  __builtin_amdgcn_global_load_lds(
      (const __attribute__((address_space(1))) void*)g,
      (__attribute__((address_space(3))) void*)l, 16, 0, 0);
}

// ------------------------------------------------- geometry + CSR (one scan) ---
__global__ __launch_bounds__(256) void pg_geom_csr(
    const float* __restrict__ pos, const float* __restrict__ adj,
    float* __restrict__ raw, float* __restrict__ Hc,
    float* __restrict__ sumA, float* __restrict__ sumAD,
    int* __restrict__ nbr, int* __restrict__ cnt)
{
  __shared__ float sp[NPT * 3];
  __shared__ float red[256 * 6];
  __shared__ int wsum[4];
  int i = blockIdx.x, t = threadIdx.x;
  for (int j = t; j < NPT * 3; j += 256) sp[j] = pos[j];
  __syncthreads();
  float px = sp[3 * i], py = sp[3 * i + 1], pz = sp[3 * i + 2];

  size_t base = (size_t)i * NPT + t * 8;
  float av[8];
  int c = 0;
  for (int u = 0; u < 8; u++) { av[u] = adj[base + u]; c += (av[u] != 0.0f); }
  int sc = c;
  int lane = t & 63;
  for (int off = 1; off < 64; off <<= 1) {
    int v = __shfl_up(sc, off);
    if (lane >= off) sc += v;
  }
  if (lane == 63) wsum[t >> 6] = sc;
  __syncthreads();
  int wprefix = 0;
  for (int w = 0; w < (t >> 6); w++) wprefix += wsum[w];
  int o = wprefix + sc - c;
  int wr = 0;
  for (int u = 0; u < 8; u++)
    if (av[u] != 0.0f) { int p = o + wr; if (p < 64) nbr[i * 64 + p] = t * 8 + u; wr++; }

  float s0 = 0, s1 = 0, s2 = 0, ax = 0, ay = 0, az = 0;
  for (int u = 0; u < 8; u++) {
    if (av[u] != 0.0f) {
      int j = t * 8 + u;
      float dx = sp[3 * j] - px, dy = sp[3 * j + 1] - py, dz = sp[3 * j + 2] - pz;
      float d2 = dx * dx + dy * dy + dz * dz + 1e-12f;
      float d = sqrtf(d2);
      s0 += 1.0f; s1 += d; s2 += d2;
      ax += sp[3 * j]; ay += sp[3 * j + 1]; az += sp[3 * j + 2];
    }
  }
  red[t * 6 + 0] = s0; red[t * 6 + 1] = s1; red[t * 6 + 2] = s2;
  red[t * 6 + 3] = ax; red[t * 6 + 4] = ay; red[t * 6 + 5] = az;
  __syncthreads();
  for (int s = 128; s > 0; s >>= 1) {
    if (t < s)
      for (int q = 0; q < 6; q++) red[t * 6 + q] += red[(t + s) * 6 + q];
    __syncthreads();
  }
  if (t == 0) {
    s0 = red[0]; s1 = red[1]; s2 = red[2]; ax = red[3]; ay = red[4]; az = red[5];
    float degc = fmaxf(s0, 1.0f);
    float dxm = ax / degc - px, dym = ay / degc - py, dzm = az / degc - pz;
    float H = 0.5f * sqrtf(dxm * dxm + dym * dym + dzm * dzm);
    float r = s1 / degc;
    float var = (s2 - 2.0f * r * s1 + r * r * s0) / degc;
    float sdev = sqrtf(var + 1e-12f);
    float k1 = H + sdev, k2 = H - sdev;
    raw[i * 6 + 0] = H;
    raw[i * 6 + 1] = k1 * k2;
    raw[i * 6 + 2] = k1;
    raw[i * 6 + 3] = k2;
    raw[i * 6 + 4] = 0.6366197723675814f * atanf((k1 + k2) / (k1 - k2 + 1e-6f));
    raw[i * 6 + 5] = sqrtf(0.5f * (k1 * k1 + k2 * k2));
    Hc[i] = H;
    sumA[i] = s0; sumAD[i] = s1;
    int tot = wsum[0] + wsum[1] + wsum[2] + wsum[3];
    cnt[i] = min(tot, 64);
  }
}

__global__ __launch_bounds__(256) void pg_stats(
    const float* __restrict__ raw, const float* __restrict__ sumA,
    const float* __restrict__ sumAD, float* __restrict__ stats)
{
  __shared__ float red[256];
  __shared__ float mean6[6];
  int t = threadIdx.x;
  float sa = 0, sad = 0;
  for (int j = t; j < NPT; j += 256) { sa += sumA[j]; sad += sumAD[j]; }
  red[t] = sa; __syncthreads();
  for (int s = 128; s > 0; s >>= 1) { if (t < s) red[t] += red[t + s]; __syncthreads(); }
  float totA = red[0]; __syncthreads();
  red[t] = sad; __syncthreads();
  for (int s = 128; s > 0; s >>= 1) { if (t < s) red[t] += red[t + s]; __syncthreads(); }
  float totAD = red[0]; __syncthreads();
  if (t == 0) {
    float sigma = fmaxf(totAD / fmaxf(totA, 1.0f), 1e-6f);
    stats[0] = 1.0f / (2.0f * sigma * sigma);
    stats[1] = sigma;
  }
  for (int q = 0; q < 6; q++) {
    float s = 0;
    for (int j = t; j < NPT; j += 256) s += raw[j * 6 + q];
    red[t] = s; __syncthreads();
    for (int k = 128; k > 0; k >>= 1) { if (t < k) red[t] += red[t + k]; __syncthreads(); }
    if (t == 0) mean6[q] = red[0] / (float)NPT;
    __syncthreads();
  }
  for (int q = 0; q < 6; q++) {
    float m = mean6[q], s = 0;
    for (int j = t; j < NPT; j += 256) { float d = raw[j * 6 + q] - m; s += d * d; }
    red[t] = s; __syncthreads();
    for (int k = 128; k > 0; k >>= 1) { if (t < k) red[t] += red[t + k]; __syncthreads(); }
    if (t == 0) {
      float sd = sqrtf(red[0] / (float)(NPT - 1));
      stats[2 + q] = m;
      stats[8 + q] = 1.0f / fmaxf(sd, 1e-6f);
    }
    __syncthreads();
  }
}

__global__ __launch_bounds__(64) void pg_wdeg(
    const float* __restrict__ pos, const int* __restrict__ nbr, const int* __restrict__ cnt,
    const float* __restrict__ stats, int2* __restrict__ pack, float* __restrict__ wdeg,
    float* __restrict__ invdeg, float* __restrict__ Dis, float* __restrict__ cvec)
{
  int i = blockIdx.x, t = threadIdx.x;
  int n = cnt[i];
  float inv2s2 = stats[0];
  float px = pos[3 * i], py = pos[3 * i + 1], pz = pos[3 * i + 2];
  float w = 0.0f;
  int j = 0;
  if (t < n) {
    j = nbr[i * 64 + t];
    float dx = pos[3 * j] - px, dy = pos[3 * j + 1] - py, dz = pos[3 * j + 2] - pz;
    float d2 = dx * dx + dy * dy + dz * dz + 1e-12f;
    w = expf(-d2 * inv2s2);
  }
  pack[i * 64 + t] = make_int2(j, __float_as_int(w));
  float s = w;
  for (int off = 1; off < 64; off <<= 1) s += __shfl_xor(s, off);
  if (t == 0) {
    float md = fmaxf(s, 1e-8f);
    wdeg[i] = s;
    invdeg[i] = 1.0f / md;
    float di = 1.0f / sqrtf(md);
    Dis[i] = di;
    cvec[i] = di * di * s;
  }
}

__global__ __launch_bounds__(64) void pg_curv_mlp(
    const float* __restrict__ pos, const float* __restrict__ raw, const float* __restrict__ stats,
    const float* __restrict__ Wc1, const float* __restrict__ bc1,
    const float* __restrict__ Wc2, const float* __restrict__ bc2,
    const float* __restrict__ Win, const float* __restrict__ b_in, float* __restrict__ h)
{
  __shared__ float feat[19];
  __shared__ float nraw[6];
  __shared__ float hid[32];
  int i = blockIdx.x, t = threadIdx.x;
  if (t < 3) feat[t] = pos[3 * i + t];
  if (t < 6) nraw[t] = (raw[i * 6 + t] - stats[2 + t]) * stats[8 + t];
  __syncthreads();
  if (t < 32) {
    float a = bc1[t];
    for (int k = 0; k < 6; k++) a += nraw[k] * Wc1[k * 32 + t];
    hid[t] = a / (1.0f + expf(-a));
  }
  __syncthreads();
  if (t < 16) {
    float a = bc2[t];
    for (int k = 0; k < 32; k++) a += hid[k] * Wc2[k * 16 + t];
    feat[3 + t] = a;
  }
  __syncthreads();
  float a = b_in[t];
  for (int k = 0; k < 19; k++) a += feat[k] * Win[k * CH + t];
  h[i * CH + t] = a;
}

// --------------- exp(L/16) Taylor-Horner: global ping-pong, XCD column stripes
__global__ __launch_bounds__(256) void pg_hinit(
    const int2* __restrict__ pack, const int* __restrict__ cnt,
    const float* __restrict__ wdeg, float* __restrict__ Y)
{
  int r = blockIdx.x, t = threadIdx.x;
  const float c0 = 1.0f / (SCL * (float)TDEG);
  float* row = Y + (size_t)r * NPT;
  for (int j = t * 4; j < NPT; j += 1024)
    *(f32x4*)(row + j) = (f32x4){0.f, 0.f, 0.f, 0.f};
  __syncthreads();
  int n = cnt[r];
  if (t < n) {
    int2 p = pack[r * 64 + t];
    row[p.x] = __int_as_float(p.y) * c0;
  }
  if (t == 0) row[r] = 1.0f - wdeg[r] * c0;
}

template <bool LAST>
__global__ __launch_bounds__(256) void pg_hstep(
    const int2* __restrict__ pack, const int* __restrict__ cnt,
    const float* __restrict__ wdeg, const float* __restrict__ Yin,
    float* __restrict__ Yout, float invc,
    bf16_t* __restrict__ Th, bf16_t* __restrict__ Tl2)
{
  int b = blockIdx.x;
  int s = b & 7, w = b >> 3;
  int t = threadIdx.x;
  int lane = t & 63, v = t >> 6;
  int c0 = s * 256 + lane * 4;
  int r0 = __builtin_amdgcn_readfirstlane(w * 8 + v * 2);
  int r1 = r0 + 1;
  int n0 = cnt[r0], n1 = cnt[r1];
  float wd0 = wdeg[r0], wd1 = wdeg[r1];
  const int2* pr0 = pack + r0 * 64;
  const int2* pr1 = pack + r1 * 64;
  f32x4 y0 = *(const f32x4*)(Yin + (size_t)r0 * NPT + c0);
  f32x4 y1 = *(const f32x4*)(Yin + (size_t)r1 * NPT + c0);
  f32x4 a0, a1, a2, a3, b0, b1, b2, b3;
#pragma unroll
  for (int e = 0; e < 4; e++) {
    a0[e] = -wd0 * y0[e]; b0[e] = -wd1 * y1[e];
    a1[e] = 0.f; a2[e] = 0.f; a3[e] = 0.f;
    b1[e] = 0.f; b2[e] = 0.f; b3[e] = 0.f;
  }
  int nmax = n0 > n1 ? n0 : n1;
  int nn = (nmax + 3) & ~3;
  for (int q = 0; q < nn; q += 4) {
    int2 pa0 = pr0[q], pa1 = pr0[q + 1], pa2 = pr0[q + 2], pa3 = pr0[q + 3];
    int2 pb0 = pr1[q], pb1 = pr1[q + 1], pb2 = pr1[q + 2], pb3 = pr1[q + 3];
    f32x4 ga0 = *(const f32x4*)(Yin + (size_t)pa0.x * NPT + c0);
    f32x4 ga1 = *(const f32x4*)(Yin + (size_t)pa1.x * NPT + c0);
    f32x4 ga2 = *(const f32x4*)(Yin + (size_t)pa2.x * NPT + c0);
    f32x4 ga3 = *(const f32x4*)(Yin + (size_t)pa3.x * NPT + c0);
    f32x4 gb0 = *(const f32x4*)(Yin + (size_t)pb0.x * NPT + c0);
    f32x4 gb1 = *(const f32x4*)(Yin + (size_t)pb1.x * NPT + c0);
    f32x4 gb2 = *(const f32x4*)(Yin + (size_t)pb2.x * NPT + c0);
    f32x4 gb3 = *(const f32x4*)(Yin + (size_t)pb3.x * NPT + c0);
    float wa0 = __int_as_float(pa0.y), wa1 = __int_as_float(pa1.y);
    float wa2 = __int_as_float(pa2.y), wa3 = __int_as_float(pa3.y);
    float wb0 = __int_as_float(pb0.y), wb1 = __int_as_float(pb1.y);
    float wb2 = __int_as_float(pb2.y), wb3 = __int_as_float(pb3.y);
#pragma unroll
    for (int e = 0; e < 4; e++) {
      a0[e] += wa0 * ga0[e]; a1[e] += wa1 * ga1[e];
      a2[e] += wa2 * ga2[e]; a3[e] += wa3 * ga3[e];
      b0[e] += wb0 * gb0[e]; b1[e] += wb1 * gb1[e];
      b2[e] += wb2 * gb2[e]; b3[e] += wb3 * gb3[e];
    }
  }
  f32x4 v0, v1;
#pragma unroll
  for (int e = 0; e < 4; e++) {
    v0[e] = ((c0 + e == r0) ? 1.0f : 0.0f) + ((a0[e] + a1[e]) + (a2[e] + a3[e])) * invc;
    v1[e] = ((c0 + e == r1) ? 1.0f : 0.0f) + ((b0[e] + b1[e]) + (b2[e] + b3[e])) * invc;
  }
  if (LAST) {
    bf16x4_t h0, l0, h1, l1;
#pragma unroll
    for (int e = 0; e < 4; e++) {
      __bf16 hb0 = (__bf16)v0[e];
      __bf16 hb1 = (__bf16)v1[e];
      h0[e] = hb0; l0[e] = (__bf16)(2.0f * (v0[e] - (float)hb0));
      h1[e] = hb1; l1[e] = (__bf16)(2.0f * (v1[e] - (float)hb1));
    }
    *(bf16x4_t*)(Th  + (size_t)r0 * NPT + c0) = h0;
    *(bf16x4_t*)(Tl2 + (size_t)r0 * NPT + c0) = l0;
    *(bf16x4_t*)(Th  + (size_t)r1 * NPT + c0) = h1;
    *(bf16x4_t*)(Tl2 + (size_t)r1 * NPT + c0) = l1;
  } else {
    *(f32x4*)(Yout + (size_t)r0 * NPT + c0) = v0;
    *(f32x4*)(Yout + (size_t)r1 * NPT + c0) = v1;
  }
}

// ---- 2-term squaring: S' = Uh*Uh^T + Uh*Ul2^T; error vs sym(U)^2 antisym.
// Tile 128x64, BK=64, grid 512, 64 KB LDS -> 2 blocks/CU.
__global__ __launch_bounds__(256) void pg_sq(
    const bf16_t* __restrict__ Ah, const bf16_t* __restrict__ Al2,
    bf16_t* __restrict__ SCh, bf16_t* __restrict__ SCl2)
{
  __shared__ __align__(16) char smem[65536];  // 2 bufs x (A 16K + Bh 8K + Bl2 8K)
  const int t = threadIdx.x;
  const int w = t >> 6, l = t & 63;
  const int lrow = l & 15, lhi = l >> 4;
  int bid = blockIdx.x;
  int sbid = (bid & 7) * 64 + (bid >> 3);     // XCD-chunked, bijective over 512
  const int by = sbid >> 5, bx = sbid & 31;   // 16 M-blocks x 32 N-blocks
  const int wr = w >> 1, wc = w & 1;          // waves 2x2 -> wave tile 64x32

  int offA[4], offB[2];
#pragma unroll
  for (int it = 0; it < 4; it++) {
    int o = it * 4096 + t * 16;
    int r = o >> 7;
    int cbyte = (o & 127) ^ ((r & 7) << 4);
    offA[it] = (by * 128 + r) * (NPT * 2) + cbyte;
  }
#pragma unroll
  for (int it = 0; it < 2; it++) {
    int o = it * 4096 + t * 16;
    int r = o >> 7;
    int cbyte = (o & 127) ^ ((r & 7) << 4);
    offB[it] = (bx * 64 + r) * (NPT * 2) + cbyte;
  }
  int aoff[4][2], boff[2][2];
#pragma unroll
  for (int m = 0; m < 4; m++) {
    int arow = wr * 64 + m * 16 + lrow;
#pragma unroll
    for (int kk = 0; kk < 2; kk++)
      aoff[m][kk] = arow * 128 + ((kk * 64 + lhi * 16) ^ ((arow & 7) << 4));
  }
#pragma unroll
  for (int n = 0; n < 2; n++) {
    int brow = wc * 32 + n * 16 + lrow;
#pragma unroll
    for (int kk = 0; kk < 2; kk++)
      boff[n][kk] = brow * 128 + ((kk * 64 + lhi * 16) ^ ((brow & 7) << 4));
  }

  f32x4 acc[4][2];
#pragma unroll
  for (int m = 0; m < 4; m++)
#pragma unroll
    for (int n = 0; n < 2; n++) acc[m][n] = (f32x4){0.f, 0.f, 0.f, 0.f};

  const int wofs = w << 10;
#pragma unroll
  for (int it = 0; it < 4; it++)
    gl_lds16((const char*)Ah + offA[it], smem + it * 4096 + wofs);
#pragma unroll
  for (int it = 0; it < 2; it++) {
    gl_lds16((const char*)Ah  + offB[it], smem + 16384 + it * 4096 + wofs);
    gl_lds16((const char*)Al2 + offB[it], smem + 24576 + it * 4096 + wofs);
  }
  __syncthreads();

  for (int ks = 0; ks < NPT / 64; ks++) {
    if (ks + 1 < NPT / 64) {
      char* nb = smem + ((ks + 1) & 1) * 32768;
      size_t kadv = (size_t)(ks + 1) * 128;
#pragma unroll
      for (int it = 0; it < 4; it++)
        gl_lds16((const char*)Ah + offA[it] + kadv, nb + it * 4096 + wofs);
#pragma unroll
      for (int it = 0; it < 2; it++) {
        gl_lds16((const char*)Ah  + offB[it] + kadv, nb + 16384 + it * 4096 + wofs);
        gl_lds16((const char*)Al2 + offB[it] + kadv, nb + 24576 + it * 4096 + wofs);
      }
    }
    const char* cb = smem + (ks & 1) * 32768;
#pragma unroll
    for (int kk = 0; kk < 2; kk++) {
      bf16x8 bh0 = *(const bf16x8*)(cb + 16384 + boff[0][kk]);
      bf16x8 bh1 = *(const bf16x8*)(cb + 16384 + boff[1][kk]);
      bf16x8 bl0 = *(const bf16x8*)(cb + 24576 + boff[0][kk]);
      bf16x8 bl1 = *(const bf16x8*)(cb + 24576 + boff[1][kk]);
#pragma unroll
      for (int m = 0; m < 4; m++) {
        bf16x8 ah = *(const bf16x8*)(cb + aoff[m][kk]);
        acc[m][0] = __builtin_amdgcn_mfma_f32_16x16x32_bf16(ah, bl0, acc[m][0], 0, 0, 0);
        acc[m][0] = __builtin_amdgcn_mfma_f32_16x16x32_bf16(ah, bh0, acc[m][0], 0, 0, 0);
        acc[m][1] = __builtin_amdgcn_mfma_f32_16x16x32_bf16(ah, bl1, acc[m][1], 0, 0, 0);
        acc[m][1] = __builtin_amdgcn_mfma_f32_16x16x32_bf16(ah, bh1, acc[m][1], 0, 0, 0);
      }
    }
    __syncthreads();
  }

  const int gr0 = by * 128 + wr * 64 + lhi * 4;
  const int gc0 = bx * 64 + wc * 32 + lrow;
#pragma unroll
  for (int m = 0; m < 4; m++) {
#pragma unroll
    for (int n = 0; n < 2; n++) {
      int gc = gc0 + n * 16;
#pragma unroll
      for (int r = 0; r < 4; r++) {
        float c = acc[m][n][r];
        __bf16 hb = (__bf16)c;
        size_t o = (size_t)(gr0 + m * 16 + r) * NPT + gc;
        SCh[o] = hb;
        SCl2[o] = (__bf16)(2.0f * (c - (float)hb));
      }
    }
  }
}

// C = (S + S^T)/2 elementwise, resplit to (h, l2). Grid (32,16).
__global__ __launch_bounds__(256) void pg_fix(
    const bf16_t* __restrict__ Sh, const bf16_t* __restrict__ Sl2,
    bf16_t* __restrict__ Oh, bf16_t* __restrict__ Ol2)
{
  __shared__ float T2[64][129];
  int bjs = blockIdx.x, bi = blockIdx.y;
  int t = threadIdx.x;
  {
    int row = t >> 2;
    int cb = (t & 3) * 32;
    size_t b2 = ((size_t)(bjs * 64 + row)) * NPT + bi * 128 + cb;
    for (int i = 0; i < 4; i++) {
      bf16x8 h8 = *(const bf16x8*)(Sh + b2 + i * 8);
      bf16x8 l8 = *(const bf16x8*)(Sl2 + b2 + i * 8);
#pragma unroll
      for (int e = 0; e < 8; e++)
        T2[row][cb + i * 8 + e] = (float)h8[e] + 0.5f * (float)l8[e];
    }
  }
  __syncthreads();
  {
    int row = t >> 1;
    int cb = (t & 1) * 32;
    size_t b1 = ((size_t)(bi * 128 + row)) * NPT + bjs * 64 + cb;
    for (int i = 0; i < 4; i++) {
      bf16x8 h8 = *(const bf16x8*)(Sh + b1 + i * 8);
      bf16x8 l8 = *(const bf16x8*)(Sl2 + b1 + i * 8);
      bf16x8 oh, ol;
#pragma unroll
      for (int e = 0; e < 8; e++) {
        float s1 = (float)h8[e] + 0.5f * (float)l8[e];
        float s2 = T2[cb + i * 8 + e][row];
        float cv = 0.5f * (s1 + s2);
        __bf16 hb = (__bf16)cv;
        oh[e] = hb;
        ol[e] = (__bf16)(2.0f * (cv - (float)hb));
      }
      *(bf16x8*)(Oh + b1 + i * 8) = oh;
      *(bf16x8*)(Ol2 + b1 + i * 8) = ol;
    }
  }
}

// -------- X (2048x64 f32) -> XT planes: h, l (true), h/2 -- LDS transpose ---
__global__ __launch_bounds__(256) void pg_splitx(
    const float* __restrict__ X, bf16_t* __restrict__ XTh,
    bf16_t* __restrict__ XTl, bf16_t* __restrict__ XTh2)
{
  __shared__ float sX[64][65];
  int t = threadIdx.x;
  int r0 = blockIdx.x * 64;
  for (int u = 0; u < 16; u++) {
    int idx = u * 256 + t;
    int r = idx >> 6, c = idx & 63;
    sX[r][c] = X[(size_t)(r0 + r) * CH + c];
  }
  __syncthreads();
  int c = t >> 6;
  int rr = t & 63;
  for (int cc = c; cc < 64; cc += 4) {
    float v = sX[rr][cc];
    __bf16 hb = (__bf16)v;
    XTh[(size_t)cc * NPT + r0 + rr] = hb;
    XTl[(size_t)cc * NPT + r0 + rr] = (__bf16)(v - (float)hb);
    XTh2[(size_t)cc * NPT + r0 + rr] = (__bf16)(0.5f * (float)hb);
  }
}

// hd[scale] = E_scale @ X via MFMA. grid (32 row-blocks, 3 scales).
__global__ __launch_bounds__(256) void pg_emm(
    const bf16_t* __restrict__ E05h, const bf16_t* __restrict__ E05l,
    const bf16_t* __restrict__ E2h,  const bf16_t* __restrict__ E2l,
    const bf16_t* __restrict__ E8h,  const bf16_t* __restrict__ E8l,
    const bf16_t* __restrict__ XTh,  const bf16_t* __restrict__ XTl,
    const bf16_t* __restrict__ XTh2, float* __restrict__ hd)
{
  __shared__ __align__(16) char smem[81920];
  const int t = threadIdx.x;
  const int w = t >> 6, l = t & 63;
  const int lrow = l & 15, lhi = l >> 4;
  const int scale = blockIdx.y;
  const bf16_t* Eh = (scale == 0) ? E05h : (scale == 1) ? E2h : E8h;
  const bf16_t* El = (scale == 0) ? E05l : (scale == 1) ? E2l : E8l;
  const int rb = blockIdx.x;

  int offA[2], offB[2];
#pragma unroll
  for (int it = 0; it < 2; it++) {
    int o = it * 4096 + t * 16;
    int r = o >> 7;
    int cb = (o & 127) ^ ((r & 7) << 4);
    offA[it] = (rb * 64 + r) * (NPT * 2) + cb;
    offB[it] = r * (NPT * 2) + cb;
  }
  int aoff[2], boff[4][2];
  {
    int arow = w * 16 + lrow;
#pragma unroll
    for (int kk = 0; kk < 2; kk++) {
      int kb = kk * 64 + lhi * 16;
      aoff[kk] = arow * 128 + (kb ^ ((arow & 7) << 4));
    }
  }
#pragma unroll
  for (int n = 0; n < 4; n++) {
    int brow = n * 16 + lrow;
#pragma unroll
    for (int kk = 0; kk < 2; kk++) {
      int kb = kk * 64 + lhi * 16;
      boff[n][kk] = brow * 128 + (kb ^ ((brow & 7) << 4));
    }
  }

  f32x4 acc[4];
#pragma unroll
  for (int n = 0; n < 4; n++) acc[n] = (f32x4){0.f, 0.f, 0.f, 0.f};

  const int lofs_w = w << 10;
#pragma unroll
  for (int it = 0; it < 2; it++) {
    int lo = it * 4096 + lofs_w;
    gl_lds16((const char*)Eh   + offA[it], smem + lo);
    gl_lds16((const char*)El   + offA[it], smem + 8192 + lo);
    gl_lds16((const char*)XTh  + offB[it], smem + 16384 + lo);
    gl_lds16((const char*)XTl  + offB[it], smem + 24576 + lo);
    gl_lds16((const char*)XTh2 + offB[it], smem + 32768 + lo);
  }
  __syncthreads();

  for (int ks = 0; ks < NPT / 64; ks++) {
    if (ks + 1 < NPT / 64) {
      char* nbuf = smem + ((ks + 1) & 1) * 40960;
      size_t kadv = (size_t)(ks + 1) * 128;
#pragma unroll
      for (int it = 0; it < 2; it++) {
        int lo = it * 4096 + lofs_w;
        gl_lds16((const char*)Eh   + offA[it] + kadv, nbuf + lo);
        gl_lds16((const char*)El   + offA[it] + kadv, nbuf + 8192 + lo);
        gl_lds16((const char*)XTh  + offB[it] + kadv, nbuf + 16384 + lo);
        gl_lds16((const char*)XTl  + offB[it] + kadv, nbuf + 24576 + lo);
        gl_lds16((const char*)XTh2 + offB[it] + kadv, nbuf + 32768 + lo);
      }
    }
    const char* cbuf = smem + (ks & 1) * 40960;
#pragma unroll
    for (int kk = 0; kk < 2; kk++) {
      bf16x8 eh  = *(const bf16x8*)(cbuf + aoff[kk]);
      bf16x8 el2 = *(const bf16x8*)(cbuf + 8192 + aoff[kk]);
#pragma unroll
      for (int n = 0; n < 4; n++) {
        bf16x8 xh  = *(const bf16x8*)(cbuf + 16384 + boff[n][kk]);
        bf16x8 xl  = *(const bf16x8*)(cbuf + 24576 + boff[n][kk]);
        bf16x8 xh2 = *(const bf16x8*)(cbuf + 32768 + boff[n][kk]);
        acc[n] = __builtin_amdgcn_mfma_f32_16x16x32_bf16(el2, xh2, acc[n], 0, 0, 0);
        acc[n] = __builtin_amdgcn_mfma_f32_16x16x32_bf16(eh, xl, acc[n], 0, 0, 0);
        acc[n] = __builtin_amdgcn_mfma_f32_16x16x32_bf16(eh, xh, acc[n], 0, 0, 0);
      }
    }
    __syncthreads();
  }

  float* Y = hd + (size_t)scale * NPT * CH;
  const int gr0 = rb * 64 + w * 16 + lhi * 4;
#pragma unroll
  for (int n = 0; n < 4; n++) {
    int gc = n * 16 + lrow;
#pragma unroll
    for (int r = 0; r < 4; r++)
      Y[(size_t)(gr0 + r) * CH + gc] = acc[n][r];
  }
}

// ------------------ layers: 4 nodes per 256-thread block, W staged in LDS ---
__global__ __launch_bounds__(256) void pg_convP(
    const int2* __restrict__ pack, const int* __restrict__ cnt,
    const float* __restrict__ invdeg, const float* __restrict__ h,
    const float* __restrict__ Ws, const float* __restrict__ bs,
    const float* __restrict__ Wn, const float* __restrict__ bn,
    const float* __restrict__ cres, float* __restrict__ out)
{
  __shared__ float WsL[4096], WnL[4096];
  __shared__ float sh[4][64], sp2[4][64];
  int t = threadIdx.x;
  int g = t >> 6, lane = t & 63;
  int i = blockIdx.x * 4 + g;
  for (int u = t * 4; u < 4096; u += 1024) {
    *(f32x4*)&WsL[u] = *(const f32x4*)&Ws[u];
    *(f32x4*)&WnL[u] = *(const f32x4*)&Wn[u];
  }
  sh[g][lane] = h[i * CH + lane];
  int n = cnt[i];
  float acc = 0.0f;
  for (int q = 0; q < n; q++) {
    int2 p = pack[i * 64 + q];
    acc += __int_as_float(p.y) * h[(size_t)p.x * CH + lane];
  }
  sp2[g][lane] = acc * invdeg[i];
  __syncthreads();
  float a = bs[lane] + bn[lane] + 0.1f * cres[0] * sh[g][lane];
  for (int k = 0; k < 64; k++)
    a += sh[g][k] * WsL[k * 64 + lane] + sp2[g][k] * WnL[k * 64 + lane];
  out[i * CH + lane] = a / (1.0f + expf(-a));
}

__global__ __launch_bounds__(256) void pg_difffuse(
    const float* __restrict__ h2, const float* __restrict__ hd,
    const float* __restrict__ dW, const float* __restrict__ db, float* __restrict__ out)
{
  __shared__ float WL[3 * 4096];
  __shared__ float shd[4][3][64];
  int t = threadIdx.x;
  int g = t >> 6, lane = t & 63;
  int i = blockIdx.x * 4 + g;
  for (int u = t * 4; u < 3 * 4096; u += 1024)
    *(f32x4*)&WL[u] = *(const f32x4*)&dW[u];
  for (int s = 0; s < 3; s++)
    shd[g][s][lane] = hd[(size_t)s * NPT * CH + i * CH + lane];
  __syncthreads();
  float a = h2[i * CH + lane] + db[lane];
  for (int s = 0; s < 3; s++) {
    const float* w = WL + s * 4096;
    for (int k = 0; k < 64; k++) a += shd[g][s][k] * w[k * 64 + lane];
  }
  out[i * CH + lane] = a;
}

// fused tanh-matvec + normalized-Laplacian gather + reaction-diffusion + LN
__global__ __launch_bounds__(256) void pg_tlr(
    const int2* __restrict__ pack, const int* __restrict__ cnt,
    const float* __restrict__ Dis, const float* __restrict__ cvec,
    const float* __restrict__ h3,
    const float* __restrict__ W1, const float* __restrict__ b1,
    const float* __restrict__ W2, const float* __restrict__ b2,
    const float* __restrict__ rdc,
    const float* __restrict__ g, const float* __restrict__ b,
    float* __restrict__ hio)
{
  __shared__ float W1L[4096], W2L[4096];
  __shared__ float sh[4][64], st[4][64];
  int t = threadIdx.x;
  int gg = t >> 6, lane = t & 63;
  int i = blockIdx.x * 4 + gg;
  for (int u = t * 4; u < 4096; u += 1024) {
    *(f32x4*)&W1L[u] = *(const f32x4*)&W1[u];
    *(f32x4*)&W2L[u] = *(const f32x4*)&W2[u];
  }
  sh[gg][lane] = h3[i * CH + lane];
  __syncthreads();
  float a = b1[lane];
  for (int k = 0; k < 64; k++) a += sh[gg][k] * W1L[k * 64 + lane];
  st[gg][lane] = tanhf(a);
  int n = cnt[i];
  float accL = 0.0f;
  for (int q = 0; q < n; q++) {
    int2 p = pack[i * 64 + q];
    accL += __int_as_float(p.y) * Dis[p.x] * h3[(size_t)p.x * CH + lane];
  }
  float tLv = accL * Dis[i] - cvec[i] * sh[gg][lane];
  __syncthreads();
  float react = b2[lane];
  for (int k = 0; k < 64; k++) react += st[gg][k] * W2L[k * 64 + lane];
  float x = sh[gg][lane] + 0.1f * (rdc[lane] * tLv + react) + hio[i * CH + lane];
  float s = x;
  for (int off = 1; off < 64; off <<= 1) s += __shfl_xor(s, off);
  float mu = s * (1.0f / 64.0f);
  float d = x - mu;
  float v = d * d;
  for (int off = 1; off < 64; off <<= 1) v += __shfl_xor(v, off);
  v *= (1.0f / 64.0f);
  hio[i * CH + lane] = d * (1.0f / sqrtf(v + 1e-5f)) * g[lane] + b[lane];
}

// ---------------------------------------------------------------- attention ---
__global__ __launch_bounds__(256) void pg_qkv(
    const float* __restrict__ h,
    const float* __restrict__ Wq, const float* __restrict__ bq,
    const float* __restrict__ Wk, const float* __restrict__ bk,
    const float* __restrict__ Wv, const float* __restrict__ bv,
    float* __restrict__ q, float* __restrict__ kb, float* __restrict__ vb)
{
  __shared__ float WqL[4096], WkL[4096], WvL[4096];
  __shared__ float sh[4][64];
  int t = threadIdx.x;
  int g = t >> 6, lane = t & 63;
  int i = blockIdx.x * 4 + g;
  for (int u = t * 4; u < 4096; u += 1024) {
    *(f32x4*)&WqL[u] = *(const f32x4*)&Wq[u];
    *(f32x4*)&WkL[u] = *(const f32x4*)&Wk[u];
    *(f32x4*)&WvL[u] = *(const f32x4*)&Wv[u];
  }
  sh[g][lane] = h[i * CH + lane];
  __syncthreads();
  float aq = bq[lane], ak = bk[lane], avv = bv[lane];
  for (int k = 0; k < 64; k++) {
    float x = sh[g][k];
    aq += x * WqL[k * 64 + lane];
    ak += x * WkL[k * 64 + lane];
    avv += x * WvL[k * 64 + lane];
  }
  q[i * CH + lane] = aq;
  kb[i * CH + lane] = ak;
  vb[i * CH + lane] = avv;
}

// CSR-masked attention + output projection + final linear, fused
__global__ __launch_bounds__(256) void pg_attn_out(
    const float* __restrict__ q, const float* __restrict__ kb, const float* __restrict__ vb,
    const int* __restrict__ nbr, const int* __restrict__ cnt,
    const float* __restrict__ Hc, const float* __restrict__ beta,
    const float* __restrict__ h,
    const float* __restrict__ Wo, const float* __restrict__ bo,
    const float* __restrict__ Wout, const float* __restrict__ bout,
    float* __restrict__ out)
{
  __shared__ float av_s[64];
  int i = blockIdx.x;
  int t = threadIdx.x;
  int head = t >> 6, lane = t & 63;
  float sp_b = logf(1.0f + expf(beta[head]));
  float hci = Hc[i];
  const float* qp = q + i * CH + head * 16;
  float qr[16];
#pragma unroll
  for (int d = 0; d < 16; d++) qr[d] = qp[d];
  int n = cnt[i];
  int K = n + 1;
  float mx = -1e30f, den = 0.0f;
  float vac[16];
#pragma unroll
  for (int d = 0; d < 16; d++) vac[d] = 0.0f;
  for (int m = lane; m < K; m += 64) {
    int j = (m == n) ? i : nbr[i * 64 + m];
    const float* kp = kb + (size_t)j * CH + head * 16;
    float sc = 0.0f;
#pragma unroll
    for (int d = 0; d < 16; d++) sc += qr[d] * kp[d];
    sc *= 0.25f;
    sc -= sp_b * fabsf(hci - Hc[j]);
    float nm = fmaxf(mx, sc);
    float corr = expf(mx - nm);
    float p = expf(sc - nm);
    den = den * corr + p;
    const float* vp = vb + (size_t)j * CH + head * 16;
#pragma unroll
    for (int d = 0; d < 16; d++) vac[d] = vac[d] * corr + p * vp[d];
    mx = nm;
  }
  for (int off = 32; off > 0; off >>= 1) {
    float omx = __shfl_down(mx, off);
    float oden = __shfl_down(den, off);
    float ov[16];
#pragma unroll
    for (int d = 0; d < 16; d++) ov[d] = __shfl_down(vac[d], off);
    float nm = fmaxf(mx, omx);
    float c1 = expf(mx - nm), c2 = expf(omx - nm);
    den = den * c1 + oden * c2;
#pragma unroll
    for (int d = 0; d < 16; d++) vac[d] = vac[d] * c1 + ov[d] * c2;
    mx = nm;
  }
  if (lane == 0) {
    float inv = 1.0f / den;
    for (int d = 0; d < 16; d++) av_s[head * 16 + d] = vac[d] * inv;
  }
  __syncthreads();
  if (t < 64) {
    float a = h[i * CH + t] + bo[t];
    for (int k = 0; k < 64; k++) a += av_s[k] * Wo[k * CH + t];
    float s = a * Wout[t];
    for (int off = 1; off < 64; off <<= 1) s += __shfl_xor(s, off);
    if (t == 0) out[i] = s + bout[0];
  }
}

// ------------------------------------------------------------------- launch ---
extern "C" void kernel_launch(void* const* d_in, const int* in_sizes, int n_in,
                              void* d_out, int out_size, void* d_ws, size_t ws_size,
                              hipStream_t stream)
{
  const float* pos   = (const float*)d_in[0];
  const float* adj   = (const float*)d_in[1];
  const float* Wc1   = (const float*)d_in[2];
  const float* bc1   = (const float*)d_in[3];
  const float* Wc2   = (const float*)d_in[4];
  const float* bc2   = (const float*)d_in[5];
  const float* Win   = (const float*)d_in[6];
  const float* b_in  = (const float*)d_in[7];
  const float* cWs   = (const float*)d_in[8];
  const float* cbs   = (const float*)d_in[9];
  const float* cWn   = (const float*)d_in[10];
  const float* cbn   = (const float*)d_in[11];
  const float* cres  = (const float*)d_in[12];
  const float* dW    = (const float*)d_in[13];
  const float* db    = (const float*)d_in[14];
  const float* rW1   = (const float*)d_in[15];
  const float* rb1   = (const float*)d_in[16];
  const float* rW2   = (const float*)d_in[17];
  const float* rb2   = (const float*)d_in[18];
  const float* rdc   = (const float*)d_in[19];
  const float* lng   = (const float*)d_in[20];
  const float* lnb   = (const float*)d_in[21];
  const float* Wq    = (const float*)d_in[22];
  const float* bq    = (const float*)d_in[23];
  const float* Wk    = (const float*)d_in[24];
  const float* bk    = (const float*)d_in[25];
  const float* Wv    = (const float*)d_in[26];
  const float* bv    = (const float*)d_in[27];
  const float* Wo    = (const float*)d_in[28];
  const float* bo    = (const float*)d_in[29];
  const float* abeta = (const float*)d_in[30];
  const float* Wout  = (const float*)d_in[31];
  const float* bout  = (const float*)d_in[32];

  const size_t NNe = (size_t)NPT * NPT;
  const size_t NC  = (size_t)NPT * CH;
  const size_t P   = NNe * 2;   // bytes per bf16 plane (8 MB)

  char* base = (char*)d_ws;
  bf16_t* E05h = (bf16_t*)(base + 0 * P);
  bf16_t* E05l = (bf16_t*)(base + 1 * P);
  bf16_t* E2h  = (bf16_t*)(base + 2 * P);
  bf16_t* E2l  = (bf16_t*)(base + 3 * P);
  bf16_t* E8h  = (bf16_t*)(base + 4 * P);
  bf16_t* E8l  = (bf16_t*)(base + 5 * P);
  bf16_t* SAh  = (bf16_t*)(base + 6 * P);
  bf16_t* SAl  = (bf16_t*)(base + 7 * P);
  bf16_t* SBh  = (bf16_t*)(base + 8 * P);
  bf16_t* SBl  = (bf16_t*)(base + 9 * P);
  // Horner ping-pong aliases planes 0-3 (dead before E05/E2 fixes write them)
  float*  M0   = (float*)(base + 0 * P);
  float*  M1   = (float*)(base + 2 * P);
  bf16_t* XTh  = (bf16_t*)(base + 12 * P);
  bf16_t* XTl  = (bf16_t*)(base + 12 * P + (size_t)NPT * CH * 2);
  bf16_t* XTh2 = (bf16_t*)(base + 12 * P + (size_t)NPT * CH * 4);
  float*  smb  = (float*)(base + 12 * P + 1024 * 1024);

  float* h   = smb;
  float* tA  = h + NC;
  float* tB  = tA + NC;
  float* hd  = tB + NC;        // 3*NC
  float* q   = hd + 3 * NC;
  float* kbf = q + NC;
  float* vbf = kbf + NC;
  float* raw = vbf + NC;
  float* sm  = raw + 8 * NPT;
  float* sumA   = sm;
  float* sumAD  = sm + NPT;
  float* wdeg   = sm + 2 * NPT;
  float* invdeg = sm + 3 * NPT;
  float* Dis    = sm + 4 * NPT;
  float* cvec   = sm + 5 * NPT;
  float* Hc     = sm + 6 * NPT;
  float* stats  = sm + 7 * NPT;
  int*   nbr    = (int*)(sm + 8 * NPT);
  int*   cnt    = nbr + (size_t)NPT * 64;
  int2*  pack   = (int2*)(cnt + NPT);

  size_t need = 12 * P + 1024 * 1024
              + (9 * NC + 16 * (size_t)NPT) * 4
              + (size_t)NPT * 64 * 4 + NPT * 4 + (size_t)NPT * 64 * 8 + 256;
  if (ws_size < need) return;

  // geometry + CSR + features
  pg_geom_csr<<<NPT, 256, 0, stream>>>(pos, adj, raw, Hc, sumA, sumAD, nbr, cnt);
  pg_stats<<<1, 256, 0, stream>>>(raw, sumA, sumAD, stats);
  pg_wdeg<<<NPT, 64, 0, stream>>>(pos, nbr, cnt, stats, pack, wdeg, invdeg, Dis, cvec);
  pg_curv_mlp<<<NPT, 64, 0, stream>>>(pos, raw, stats, Wc1, bc1, Wc2, bc2, Win, b_in, h);

  // T = exp(L/16): global ping-pong Taylor-Horner, XCD column stripes
  pg_hinit<<<NPT, 256, 0, stream>>>(pack, cnt, wdeg, M0);
  float* cur = M0;
  float* nxt = M1;
  for (int k = TDEG - 1; k >= 2; k--) {
    pg_hstep<false><<<NPT, 256, 0, stream>>>(pack, cnt, wdeg, cur, nxt,
                                             1.0f / (SCL * (float)k), nullptr, nullptr);
    float* tmp = cur; cur = nxt; nxt = tmp;
  }
  pg_hstep<true><<<NPT, 256, 0, stream>>>(pack, cnt, wdeg, cur, nullptr,
                                          1.0f / SCL, SAh, SAl);

  // squaring chain: 7 x 2-term squarings, fixes ONLY at consumed outputs.
  dim3 gfix(32, 16);
  pg_sq <<<512, 256, 0, stream>>>(SAh, SAl, SBh, SBl);     // U1 = L/8 (unfixed)
  pg_sq <<<512, 256, 0, stream>>>(SBh, SBl, SAh, SAl);     // U2 = L/4 (unfixed)
  pg_sq <<<512, 256, 0, stream>>>(SAh, SAl, SBh, SBl);     // U3 = L/2
  pg_fix<<<gfix, 256, 0, stream>>>(SBh, SBl, E05h, E05l);  // E05 = sym(U3)
  pg_sq <<<512, 256, 0, stream>>>(E05h, E05l, SAh, SAl);   // U4 = L (unfixed)
  pg_sq <<<512, 256, 0, stream>>>(SAh, SAl, SBh, SBl);     // U5 = 2L
  pg_fix<<<gfix, 256, 0, stream>>>(SBh, SBl, E2h, E2l);    // E2 = sym(U5)
  pg_sq <<<512, 256, 0, stream>>>(E2h, E2l, SAh, SAl);     // U6 = 4L (unfixed)
  pg_sq <<<512, 256, 0, stream>>>(SAh, SAl, SBh, SBl);     // U7 = 8L
  pg_fix<<<gfix, 256, 0, stream>>>(SBh, SBl, E8h, E8l);    // E8 = sym(U7)

  // NL layers
  for (int i = 0; i < 4; i++) {
    pg_convP<<<NPT / 4, 256, 0, stream>>>(pack, cnt, invdeg, h,
                                          cWs + i * 4096, cbs + i * 64,
                                          cWn + i * 4096, cbn + i * 64, cres + i, tA);
    float* h3 = tA;
    if ((i & 1) == 0) {
      int j = i >> 1;
      pg_splitx<<<32, 256, 0, stream>>>(tA, XTh, XTl, XTh2);
      pg_emm<<<dim3(32, 3), 256, 0, stream>>>(E05h, E05l, E2h, E2l, E8h, E8l,
                                              XTh, XTl, XTh2, hd);
      pg_difffuse<<<NPT / 4, 256, 0, stream>>>(tA, hd, dW + j * 3 * 4096, db + j * 64, tB);
      h3 = tB;
    }
    pg_tlr<<<NPT / 4, 256, 0, stream>>>(pack, cnt, Dis, cvec, h3,
                                        rW1 + i * 4096, rb1 + i * 64,
                                        rW2 + i * 4096, rb2 + i * 64,
                                        rdc + i * 64, lng + i * 64, lnb + i * 64, h);
  }

  // attention + output
  pg_qkv<<<NPT / 4, 256, 0, stream>>>(h, Wq, bq, Wk, bk, Wv, bv, q, kbf, vbf);
  pg_attn_out<<<NPT, 256, 0, stream>>>(q, kbf, vbf, nbr, cnt, Hc, abeta,
                                       h, Wo, bo, Wout, bout, (float*)d_out);
}

// Round 13
// 684.476 us; speedup vs baseline: 1.0626x; 1.0626x over previous
//
#include <hip/hip_runtime.h>
#include <math.h>

#define NPT 2048
#define CH 64
constexpr int TDEG = 13;        // Taylor degree for exp(L/16)
constexpr float SCL = 16.0f;    // scaling denominator

// Storage convention: matrix plane-pairs are (h, l2), value = h + l2/2.
// 2-term squaring computes S' = Uh*Uh^T + Uh*Ul2^T whose error vs sym(U)^2 is
// ANTISYMMETRIC; intermediate squarings stay unfixed, one symmetrize-fix per
// consumed output (E05, E2, E8).

typedef __bf16 bf16_t;
typedef __bf16 bf16x8 __attribute__((ext_vector_type(8)));
typedef __bf16 bf16x4_t __attribute__((ext_vector_type(4)));
typedef float f32x4 __attribute__((ext_vector_type(4)));

__device__ __forceinline__ void gl_lds16(const void* g, void* l) {
  __builtin_amdgcn_global_load_lds(
      (const __attribute__((address_space(1))) void*)g,
      (__attribute__((address_space(3))) void*)l, 16, 0, 0);
}

// ------------------------------------------------- geometry + CSR (one scan) ---
__global__ __launch_bounds__(256) void pg_geom_csr(
    const float* __restrict__ pos, const float* __restrict__ adj,
    float* __restrict__ raw, float* __restrict__ Hc,
    float* __restrict__ sumA, float* __restrict__ sumAD,
    int* __restrict__ nbr, int* __restrict__ cnt)
{
  __shared__ float sp[NPT * 3];
  __shared__ float red[256 * 6];
  __shared__ int wsum[4];
  int i = blockIdx.x, t = threadIdx.x;
  for (int j = t; j < NPT * 3; j += 256) sp[j] = pos[j];
  __syncthreads();
  float px = sp[3 * i], py = sp[3 * i + 1], pz = sp[3 * i + 2];

  size_t base = (size_t)i * NPT + t * 8;
  float av[8];
  int c = 0;
  for (int u = 0; u < 8; u++) { av[u] = adj[base + u]; c += (av[u] != 0.0f); }
  int sc = c;
  int lane = t & 63;
  for (int off = 1; off < 64; off <<= 1) {
    int v = __shfl_up(sc, off);
    if (lane >= off) sc += v;
  }
  if (lane == 63) wsum[t >> 6] = sc;
  __syncthreads();
  int wprefix = 0;
  for (int w = 0; w < (t >> 6); w++) wprefix += wsum[w];
  int o = wprefix + sc - c;
  int wr = 0;
  for (int u = 0; u < 8; u++)
    if (av[u] != 0.0f) { int p = o + wr; if (p < 64) nbr[i * 64 + p] = t * 8 + u; wr++; }

  float s0 = 0, s1 = 0, s2 = 0, ax = 0, ay = 0, az = 0;
  for (int u = 0; u < 8; u++) {
    if (av[u] != 0.0f) {
      int j = t * 8 + u;
      float dx = sp[3 * j] - px, dy = sp[3 * j + 1] - py, dz = sp[3 * j + 2] - pz;
      float d2 = dx * dx + dy * dy + dz * dz + 1e-12f;
      float d = sqrtf(d2);
      s0 += 1.0f; s1 += d; s2 += d2;
      ax += sp[3 * j]; ay += sp[3 * j + 1]; az += sp[3 * j + 2];
    }
  }
  red[t * 6 + 0] = s0; red[t * 6 + 1] = s1; red[t * 6 + 2] = s2;
  red[t * 6 + 3] = ax; red[t * 6 + 4] = ay; red[t * 6 + 5] = az;
  __syncthreads();
  for (int s = 128; s > 0; s >>= 1) {
    if (t < s)
      for (int q = 0; q < 6; q++) red[t * 6 + q] += red[(t + s) * 6 + q];
    __syncthreads();
  }
  if (t == 0) {
    s0 = red[0]; s1 = red[1]; s2 = red[2]; ax = red[3]; ay = red[4]; az = red[5];
    float degc = fmaxf(s0, 1.0f);
    float dxm = ax / degc - px, dym = ay / degc - py, dzm = az / degc - pz;
    float H = 0.5f * sqrtf(dxm * dxm + dym * dym + dzm * dzm);
    float r = s1 / degc;
    float var = (s2 - 2.0f * r * s1 + r * r * s0) / degc;
    float sdev = sqrtf(var + 1e-12f);
    float k1 = H + sdev, k2 = H - sdev;
    raw[i * 6 + 0] = H;
    raw[i * 6 + 1] = k1 * k2;
    raw[i * 6 + 2] = k1;
    raw[i * 6 + 3] = k2;
    raw[i * 6 + 4] = 0.6366197723675814f * atanf((k1 + k2) / (k1 - k2 + 1e-6f));
    raw[i * 6 + 5] = sqrtf(0.5f * (k1 * k1 + k2 * k2));
    Hc[i] = H;
    sumA[i] = s0; sumAD[i] = s1;
    int tot = wsum[0] + wsum[1] + wsum[2] + wsum[3];
    cnt[i] = min(tot, 64);
  }
}

__global__ __launch_bounds__(256) void pg_stats(
    const float* __restrict__ raw, const float* __restrict__ sumA,
    const float* __restrict__ sumAD, float* __restrict__ stats)
{
  __shared__ float red[256];
  __shared__ float mean6[6];
  int t = threadIdx.x;
  float sa = 0, sad = 0;
  for (int j = t; j < NPT; j += 256) { sa += sumA[j]; sad += sumAD[j]; }
  red[t] = sa; __syncthreads();
  for (int s = 128; s > 0; s >>= 1) { if (t < s) red[t] += red[t + s]; __syncthreads(); }
  float totA = red[0]; __syncthreads();
  red[t] = sad; __syncthreads();
  for (int s = 128; s > 0; s >>= 1) { if (t < s) red[t] += red[t + s]; __syncthreads(); }
  float totAD = red[0]; __syncthreads();
  if (t == 0) {
    float sigma = fmaxf(totAD / fmaxf(totA, 1.0f), 1e-6f);
    stats[0] = 1.0f / (2.0f * sigma * sigma);
    stats[1] = sigma;
  }
  for (int q = 0; q < 6; q++) {
    float s = 0;
    for (int j = t; j < NPT; j += 256) s += raw[j * 6 + q];
    red[t] = s; __syncthreads();
    for (int k = 128; k > 0; k >>= 1) { if (t < k) red[t] += red[t + k]; __syncthreads(); }
    if (t == 0) mean6[q] = red[0] / (float)NPT;
    __syncthreads();
  }
  for (int q = 0; q < 6; q++) {
    float m = mean6[q], s = 0;
    for (int j = t; j < NPT; j += 256) { float d = raw[j * 6 + q] - m; s += d * d; }
    red[t] = s; __syncthreads();
    for (int k = 128; k > 0; k >>= 1) { if (t < k) red[t] += red[t + k]; __syncthreads(); }
    if (t == 0) {
      float sd = sqrtf(red[0] / (float)(NPT - 1));
      stats[2 + q] = m;
      stats[8 + q] = 1.0f / fmaxf(sd, 1e-6f);
    }
    __syncthreads();
  }
}

__global__ __launch_bounds__(64) void pg_wdeg(
    const float* __restrict__ pos, const int* __restrict__ nbr, const int* __restrict__ cnt,
    const float* __restrict__ stats, int2* __restrict__ pack, float* __restrict__ wdeg,
    float* __restrict__ invdeg, float* __restrict__ Dis, float* __restrict__ cvec)
{
  int i = blockIdx.x, t = threadIdx.x;
  int n = cnt[i];
  float inv2s2 = stats[0];
  float px = pos[3 * i], py = pos[3 * i + 1], pz = pos[3 * i + 2];
  float w = 0.0f;
  int j = 0;
  if (t < n) {
    j = nbr[i * 64 + t];
    float dx = pos[3 * j] - px, dy = pos[3 * j + 1] - py, dz = pos[3 * j + 2] - pz;
    float d2 = dx * dx + dy * dy + dz * dz + 1e-12f;
    w = expf(-d2 * inv2s2);
  }
  pack[i * 64 + t] = make_int2(j, __float_as_int(w));
  float s = w;
  for (int off = 1; off < 64; off <<= 1) s += __shfl_xor(s, off);
  if (t == 0) {
    float md = fmaxf(s, 1e-8f);
    wdeg[i] = s;
    invdeg[i] = 1.0f / md;
    float di = 1.0f / sqrtf(md);
    Dis[i] = di;
    cvec[i] = di * di * s;
  }
}

__global__ __launch_bounds__(64) void pg_curv_mlp(
    const float* __restrict__ pos, const float* __restrict__ raw, const float* __restrict__ stats,
    const float* __restrict__ Wc1, const float* __restrict__ bc1,
    const float* __restrict__ Wc2, const float* __restrict__ bc2,
    const float* __restrict__ Win, const float* __restrict__ b_in, float* __restrict__ h)
{
  __shared__ float feat[19];
  __shared__ float nraw[6];
  __shared__ float hid[32];
  int i = blockIdx.x, t = threadIdx.x;
  if (t < 3) feat[t] = pos[3 * i + t];
  if (t < 6) nraw[t] = (raw[i * 6 + t] - stats[2 + t]) * stats[8 + t];
  __syncthreads();
  if (t < 32) {
    float a = bc1[t];
    for (int k = 0; k < 6; k++) a += nraw[k] * Wc1[k * 32 + t];
    hid[t] = a / (1.0f + expf(-a));
  }
  __syncthreads();
  if (t < 16) {
    float a = bc2[t];
    for (int k = 0; k < 32; k++) a += hid[k] * Wc2[k * 16 + t];
    feat[3 + t] = a;
  }
  __syncthreads();
  float a = b_in[t];
  for (int k = 0; k < 19; k++) a += feat[k] * Win[k * CH + t];
  h[i * CH + t] = a;
}

// --------------- exp(L/16) Taylor-Horner: global ping-pong, XCD column stripes
__global__ __launch_bounds__(256) void pg_hinit(
    const int2* __restrict__ pack, const int* __restrict__ cnt,
    const float* __restrict__ wdeg, float* __restrict__ Y)
{
  int r = blockIdx.x, t = threadIdx.x;
  const float c0 = 1.0f / (SCL * (float)TDEG);
  float* row = Y + (size_t)r * NPT;
  for (int j = t * 4; j < NPT; j += 1024)
    *(f32x4*)(row + j) = (f32x4){0.f, 0.f, 0.f, 0.f};
  __syncthreads();
  int n = cnt[r];
  if (t < n) {
    int2 p = pack[r * 64 + t];
    row[p.x] = __int_as_float(p.y) * c0;
  }
  if (t == 0) row[r] = 1.0f - wdeg[r] * c0;
}

template <bool LAST>
__global__ __launch_bounds__(256) void pg_hstep(
    const int2* __restrict__ pack, const int* __restrict__ cnt,
    const float* __restrict__ wdeg, const float* __restrict__ Yin,
    float* __restrict__ Yout, float invc,
    bf16_t* __restrict__ Th, bf16_t* __restrict__ Tl2)
{
  int b = blockIdx.x;
  int s = b & 7, w = b >> 3;
  int t = threadIdx.x;
  int lane = t & 63, v = t >> 6;
  int c0 = s * 256 + lane * 4;
  int r0 = __builtin_amdgcn_readfirstlane(w * 8 + v * 2);
  int r1 = r0 + 1;
  int n0 = cnt[r0], n1 = cnt[r1];
  float wd0 = wdeg[r0], wd1 = wdeg[r1];
  const int2* pr0 = pack + r0 * 64;
  const int2* pr1 = pack + r1 * 64;
  f32x4 y0 = *(const f32x4*)(Yin + (size_t)r0 * NPT + c0);
  f32x4 y1 = *(const f32x4*)(Yin + (size_t)r1 * NPT + c0);
  f32x4 a0, a1, a2, a3, b0, b1, b2, b3;
#pragma unroll
  for (int e = 0; e < 4; e++) {
    a0[e] = -wd0 * y0[e]; b0[e] = -wd1 * y1[e];
    a1[e] = 0.f; a2[e] = 0.f; a3[e] = 0.f;
    b1[e] = 0.f; b2[e] = 0.f; b3[e] = 0.f;
  }
  int nmax = n0 > n1 ? n0 : n1;
  int nn = (nmax + 3) & ~3;
  for (int q = 0; q < nn; q += 4) {
    int2 pa0 = pr0[q], pa1 = pr0[q + 1], pa2 = pr0[q + 2], pa3 = pr0[q + 3];
    int2 pb0 = pr1[q], pb1 = pr1[q + 1], pb2 = pr1[q + 2], pb3 = pr1[q + 3];
    f32x4 ga0 = *(const f32x4*)(Yin + (size_t)pa0.x * NPT + c0);
    f32x4 ga1 = *(const f32x4*)(Yin + (size_t)pa1.x * NPT + c0);
    f32x4 ga2 = *(const f32x4*)(Yin + (size_t)pa2.x * NPT + c0);
    f32x4 ga3 = *(const f32x4*)(Yin + (size_t)pa3.x * NPT + c0);
    f32x4 gb0 = *(const f32x4*)(Yin + (size_t)pb0.x * NPT + c0);
    f32x4 gb1 = *(const f32x4*)(Yin + (size_t)pb1.x * NPT + c0);
    f32x4 gb2 = *(const f32x4*)(Yin + (size_t)pb2.x * NPT + c0);
    f32x4 gb3 = *(const f32x4*)(Yin + (size_t)pb3.x * NPT + c0);
    float wa0 = __int_as_float(pa0.y), wa1 = __int_as_float(pa1.y);
    float wa2 = __int_as_float(pa2.y), wa3 = __int_as_float(pa3.y);
    float wb0 = __int_as_float(pb0.y), wb1 = __int_as_float(pb1.y);
    float wb2 = __int_as_float(pb2.y), wb3 = __int_as_float(pb3.y);
#pragma unroll
    for (int e = 0; e < 4; e++) {
      a0[e] += wa0 * ga0[e]; a1[e] += wa1 * ga1[e];
      a2[e] += wa2 * ga2[e]; a3[e] += wa3 * ga3[e];
      b0[e] += wb0 * gb0[e]; b1[e] += wb1 * gb1[e];
      b2[e] += wb2 * gb2[e]; b3[e] += wb3 * gb3[e];
    }
  }
  f32x4 v0, v1;
#pragma unroll
  for (int e = 0; e < 4; e++) {
    v0[e] = ((c0 + e == r0) ? 1.0f : 0.0f) + ((a0[e] + a1[e]) + (a2[e] + a3[e])) * invc;
    v1[e] = ((c0 + e == r1) ? 1.0f : 0.0f) + ((b0[e] + b1[e]) + (b2[e] + b3[e])) * invc;
  }
  if (LAST) {
    bf16x4_t h0, l0, h1, l1;
#pragma unroll
    for (int e = 0; e < 4; e++) {
      __bf16 hb0 = (__bf16)v0[e];
      __bf16 hb1 = (__bf16)v1[e];
      h0[e] = hb0; l0[e] = (__bf16)(2.0f * (v0[e] - (float)hb0));
      h1[e] = hb1; l1[e] = (__bf16)(2.0f * (v1[e] - (float)hb1));
    }
    *(bf16x4_t*)(Th  + (size_t)r0 * NPT + c0) = h0;
    *(bf16x4_t*)(Tl2 + (size_t)r0 * NPT + c0) = l0;
    *(bf16x4_t*)(Th  + (size_t)r1 * NPT + c0) = h1;
    *(bf16x4_t*)(Tl2 + (size_t)r1 * NPT + c0) = l1;
  } else {
    *(f32x4*)(Yout + (size_t)r0 * NPT + c0) = v0;
    *(f32x4*)(Yout + (size_t)r1 * NPT + c0) = v1;
  }
}

// ---- 2-term squaring: S' = Uh*Uh^T + Uh*Ul2^T; error vs sym(U)^2 antisym.
// Tile 128x64, BK=64, grid 512, 64 KB LDS -> 2 blocks/CU.
__global__ __launch_bounds__(256) void pg_sq(
    const bf16_t* __restrict__ Ah, const bf16_t* __restrict__ Al2,
    bf16_t* __restrict__ SCh, bf16_t* __restrict__ SCl2)
{
  __shared__ __align__(16) char smem[65536];  // 2 bufs x (A 16K + Bh 8K + Bl2 8K)
  const int t = threadIdx.x;
  const int w = t >> 6, l = t & 63;
  const int lrow = l & 15, lhi = l >> 4;
  int bid = blockIdx.x;
  int sbid = (bid & 7) * 64 + (bid >> 3);     // XCD-chunked, bijective over 512
  const int by = sbid >> 5, bx = sbid & 31;   // 16 M-blocks x 32 N-blocks
  const int wr = w >> 1, wc = w & 1;          // waves 2x2 -> wave tile 64x32

  int offA[4], offB[2];
#pragma unroll
  for (int it = 0; it < 4; it++) {
    int o = it * 4096 + t * 16;
    int r = o >> 7;
    int cbyte = (o & 127) ^ ((r & 7) << 4);
    offA[it] = (by * 128 + r) * (NPT * 2) + cbyte;
  }
#pragma unroll
  for (int it = 0; it < 2; it++) {
    int o = it * 4096 + t * 16;
    int r = o >> 7;
    int cbyte = (o & 127) ^ ((r & 7) << 4);
    offB[it] = (bx * 64 + r) * (NPT * 2) + cbyte;
  }
  int aoff[4][2], boff[2][2];
#pragma unroll
  for (int m = 0; m < 4; m++) {
    int arow = wr * 64 + m * 16 + lrow;
#pragma unroll
    for (int kk = 0; kk < 2; kk++)
      aoff[m][kk] = arow * 128 + ((kk * 64 + lhi * 16) ^ ((arow & 7) << 4));
  }
#pragma unroll
  for (int n = 0; n < 2; n++) {
    int brow = wc * 32 + n * 16 + lrow;
#pragma unroll
    for (int kk = 0; kk < 2; kk++)
      boff[n][kk] = brow * 128 + ((kk * 64 + lhi * 16) ^ ((brow & 7) << 4));
  }

  f32x4 acc[4][2];
#pragma unroll
  for (int m = 0; m < 4; m++)
#pragma unroll
    for (int n = 0; n < 2; n++) acc[m][n] = (f32x4){0.f, 0.f, 0.f, 0.f};

  const int wofs = w << 10;
#pragma unroll
  for (int it = 0; it < 4; it++)
    gl_lds16((const char*)Ah + offA[it], smem + it * 4096 + wofs);
#pragma unroll
  for (int it = 0; it < 2; it++) {
    gl_lds16((const char*)Ah  + offB[it], smem + 16384 + it * 4096 + wofs);
    gl_lds16((const char*)Al2 + offB[it], smem + 24576 + it * 4096 + wofs);
  }
  __syncthreads();

  for (int ks = 0; ks < NPT / 64; ks++) {
    if (ks + 1 < NPT / 64) {
      char* nb = smem + ((ks + 1) & 1) * 32768;
      size_t kadv = (size_t)(ks + 1) * 128;
#pragma unroll
      for (int it = 0; it < 4; it++)
        gl_lds16((const char*)Ah + offA[it] + kadv, nb + it * 4096 + wofs);
#pragma unroll
      for (int it = 0; it < 2; it++) {
        gl_lds16((const char*)Ah  + offB[it] + kadv, nb + 16384 + it * 4096 + wofs);
        gl_lds16((const char*)Al2 + offB[it] + kadv, nb + 24576 + it * 4096 + wofs);
      }
    }
    const char* cb = smem + (ks & 1) * 32768;
#pragma unroll
    for (int kk = 0; kk < 2; kk++) {
      bf16x8 bh0 = *(const bf16x8*)(cb + 16384 + boff[0][kk]);
      bf16x8 bh1 = *(const bf16x8*)(cb + 16384 + boff[1][kk]);
      bf16x8 bl0 = *(const bf16x8*)(cb + 24576 + boff[0][kk]);
      bf16x8 bl1 = *(const bf16x8*)(cb + 24576 + boff[1][kk]);
#pragma unroll
      for (int m = 0; m < 4; m++) {
        bf16x8 ah = *(const bf16x8*)(cb + aoff[m][kk]);
        acc[m][0] = __builtin_amdgcn_mfma_f32_16x16x32_bf16(ah, bl0, acc[m][0], 0, 0, 0);
        acc[m][0] = __builtin_amdgcn_mfma_f32_16x16x32_bf16(ah, bh0, acc[m][0], 0, 0, 0);
        acc[m][1] = __builtin_amdgcn_mfma_f32_16x16x32_bf16(ah, bl1, acc[m][1], 0, 0, 0);
        acc[m][1] = __builtin_amdgcn_mfma_f32_16x16x32_bf16(ah, bh1, acc[m][1], 0, 0, 0);
      }
    }
    __syncthreads();
  }

  const int gr0 = by * 128 + wr * 64 + lhi * 4;
  const int gc0 = bx * 64 + wc * 32 + lrow;
#pragma unroll
  for (int m = 0; m < 4; m++) {
#pragma unroll
    for (int n = 0; n < 2; n++) {
      int gc = gc0 + n * 16;
#pragma unroll
      for (int r = 0; r < 4; r++) {
        float c = acc[m][n][r];
        __bf16 hb = (__bf16)c;
        size_t o = (size_t)(gr0 + m * 16 + r) * NPT + gc;
        SCh[o] = hb;
        SCl2[o] = (__bf16)(2.0f * (c - (float)hb));
      }
    }
  }
}

// C = (S + S^T)/2 elementwise, resplit to (h, l2). Grid (32,16).
__global__ __launch_bounds__(256) void pg_fix(
    const bf16_t* __restrict__ Sh, const bf16_t* __restrict__ Sl2,
    bf16_t* __restrict__ Oh, bf16_t* __restrict__ Ol2)
{
  __shared__ float T2[64][129];
  int bjs = blockIdx.x, bi = blockIdx.y;
  int t = threadIdx.x;
  {
    int row = t >> 2;
    int cb = (t & 3) * 32;
    size_t b2 = ((size_t)(bjs * 64 + row)) * NPT + bi * 128 + cb;
    for (int i = 0; i < 4; i++) {
      bf16x8 h8 = *(const bf16x8*)(Sh + b2 + i * 8);
      bf16x8 l8 = *(const bf16x8*)(Sl2 + b2 + i * 8);
#pragma unroll
      for (int e = 0; e < 8; e++)
        T2[row][cb + i * 8 + e] = (float)h8[e] + 0.5f * (float)l8[e];
    }
  }
  __syncthreads();
  {
    int row = t >> 1;
    int cb = (t & 1) * 32;
    size_t b1 = ((size_t)(bi * 128 + row)) * NPT + bjs * 64 + cb;
    for (int i = 0; i < 4; i++) {
      bf16x8 h8 = *(const bf16x8*)(Sh + b1 + i * 8);
      bf16x8 l8 = *(const bf16x8*)(Sl2 + b1 + i * 8);
      bf16x8 oh, ol;
#pragma unroll
      for (int e = 0; e < 8; e++) {
        float s1 = (float)h8[e] + 0.5f * (float)l8[e];
        float s2 = T2[cb + i * 8 + e][row];
        float cv = 0.5f * (s1 + s2);
        __bf16 hb = (__bf16)cv;
        oh[e] = hb;
        ol[e] = (__bf16)(2.0f * (cv - (float)hb));
      }
      *(bf16x8*)(Oh + b1 + i * 8) = oh;
      *(bf16x8*)(Ol2 + b1 + i * 8) = ol;
    }
  }
}

// -------- X (2048x64 f32) -> XT planes: h, l (true), h/2 -- LDS transpose ---
__global__ __launch_bounds__(256) void pg_splitx(
    const float* __restrict__ X, bf16_t* __restrict__ XTh,
    bf16_t* __restrict__ XTl, bf16_t* __restrict__ XTh2)
{
  __shared__ float sX[64][65];
  int t = threadIdx.x;
  int r0 = blockIdx.x * 64;
  for (int u = 0; u < 16; u++) {
    int idx = u * 256 + t;
    int r = idx >> 6, c = idx & 63;
    sX[r][c] = X[(size_t)(r0 + r) * CH + c];
  }
  __syncthreads();
  int c = t >> 6;
  int rr = t & 63;
  for (int cc = c; cc < 64; cc += 4) {
    float v = sX[rr][cc];
    __bf16 hb = (__bf16)v;
    XTh[(size_t)cc * NPT + r0 + rr] = hb;
    XTl[(size_t)cc * NPT + r0 + rr] = (__bf16)(v - (float)hb);
    XTh2[(size_t)cc * NPT + r0 + rr] = (__bf16)(0.5f * (float)hb);
  }
}

// hd[scale] = E_scale @ X via MFMA. grid (32 row-blocks, 3 scales).
__global__ __launch_bounds__(256) void pg_emm(
    const bf16_t* __restrict__ E05h, const bf16_t* __restrict__ E05l,
    const bf16_t* __restrict__ E2h,  const bf16_t* __restrict__ E2l,
    const bf16_t* __restrict__ E8h,  const bf16_t* __restrict__ E8l,
    const bf16_t* __restrict__ XTh,  const bf16_t* __restrict__ XTl,
    const bf16_t* __restrict__ XTh2, float* __restrict__ hd)
{
  __shared__ __align__(16) char smem[81920];
  const int t = threadIdx.x;
  const int w = t >> 6, l = t & 63;
  const int lrow = l & 15, lhi = l >> 4;
  const int scale = blockIdx.y;
  const bf16_t* Eh = (scale == 0) ? E05h : (scale == 1) ? E2h : E8h;
  const bf16_t* El = (scale == 0) ? E05l : (scale == 1) ? E2l : E8l;
  const int rb = blockIdx.x;

  int offA[2], offB[2];
#pragma unroll
  for (int it = 0; it < 2; it++) {
    int o = it * 4096 + t * 16;
    int r = o >> 7;
    int cb = (o & 127) ^ ((r & 7) << 4);
    offA[it] = (rb * 64 + r) * (NPT * 2) + cb;
    offB[it] = r * (NPT * 2) + cb;
  }
  int aoff[2], boff[4][2];
  {
    int arow = w * 16 + lrow;
#pragma unroll
    for (int kk = 0; kk < 2; kk++) {
      int kb = kk * 64 + lhi * 16;
      aoff[kk] = arow * 128 + (kb ^ ((arow & 7) << 4));
    }
  }
#pragma unroll
  for (int n = 0; n < 4; n++) {
    int brow = n * 16 + lrow;
#pragma unroll
    for (int kk = 0; kk < 2; kk++) {
      int kb = kk * 64 + lhi * 16;
      boff[n][kk] = brow * 128 + (kb ^ ((brow & 7) << 4));
    }
  }

  f32x4 acc[4];
#pragma unroll
  for (int n = 0; n < 4; n++) acc[n] = (f32x4){0.f, 0.f, 0.f, 0.f};

  const int lofs_w = w << 10;
#pragma unroll
  for (int it = 0; it < 2; it++) {
    int lo = it * 4096 + lofs_w;
    gl_lds16((const char*)Eh   + offA[it], smem + lo);
    gl_lds16((const char*)El   + offA[it], smem + 8192 + lo);
    gl_lds16((const char*)XTh  + offB[it], smem + 16384 + lo);
    gl_lds16((const char*)XTl  + offB[it], smem + 24576 + lo);
    gl_lds16((const char*)XTh2 + offB[it], smem + 32768 + lo);
  }
  __syncthreads();

  for (int ks = 0; ks < NPT / 64; ks++) {
    if (ks + 1 < NPT / 64) {
      char* nbuf = smem + ((ks + 1) & 1) * 40960;
      size_t kadv = (size_t)(ks + 1) * 128;
#pragma unroll
      for (int it = 0; it < 2; it++) {
        int lo = it * 4096 + lofs_w;
        gl_lds16((const char*)Eh   + offA[it] + kadv, nbuf + lo);
        gl_lds16((const char*)El   + offA[it] + kadv, nbuf + 8192 + lo);
        gl_lds16((const char*)XTh  + offB[it] + kadv, nbuf + 16384 + lo);
        gl_lds16((const char*)XTl  + offB[it] + kadv, nbuf + 24576 + lo);
        gl_lds16((const char*)XTh2 + offB[it] + kadv, nbuf + 32768 + lo);
      }
    }
    const char* cbuf = smem + (ks & 1) * 40960;
#pragma unroll
    for (int kk = 0; kk < 2; kk++) {
      bf16x8 eh  = *(const bf16x8*)(cbuf + aoff[kk]);
      bf16x8 el2 = *(const bf16x8*)(cbuf + 8192 + aoff[kk]);
#pragma unroll
      for (int n = 0; n < 4; n++) {
        bf16x8 xh  = *(const bf16x8*)(cbuf + 16384 + boff[n][kk]);
        bf16x8 xl  = *(const bf16x8*)(cbuf + 24576 + boff[n][kk]);
        bf16x8 xh2 = *(const bf16x8*)(cbuf + 32768 + boff[n][kk]);
        acc[n] = __builtin_amdgcn_mfma_f32_16x16x32_bf16(el2, xh2, acc[n], 0, 0, 0);
        acc[n] = __builtin_amdgcn_mfma_f32_16x16x32_bf16(eh, xl, acc[n], 0, 0, 0);
        acc[n] = __builtin_amdgcn_mfma_f32_16x16x32_bf16(eh, xh, acc[n], 0, 0, 0);
      }
    }
    __syncthreads();
  }

  float* Y = hd + (size_t)scale * NPT * CH;
  const int gr0 = rb * 64 + w * 16 + lhi * 4;
#pragma unroll
  for (int n = 0; n < 4; n++) {
    int gc = n * 16 + lrow;
#pragma unroll
    for (int r = 0; r < 4; r++)
      Y[(size_t)(gr0 + r) * CH + gc] = acc[n][r];
  }
}

// ------------------------------------------------------------------- layers ---
__global__ __launch_bounds__(64) void pg_convP(
    const int2* __restrict__ pack, const int* __restrict__ cnt,
    const float* __restrict__ invdeg, const float* __restrict__ h,
    const float* __restrict__ Ws, const float* __restrict__ bs,
    const float* __restrict__ Wn, const float* __restrict__ bn,
    const float* __restrict__ cres, float* __restrict__ out)
{
  __shared__ float sh[64], sp2[64];
  int i = blockIdx.x, t = threadIdx.x;
  sh[t] = h[i * CH + t];
  int n = cnt[i];
  float acc = 0.0f;
  for (int q = 0; q < n; q++) {
    int2 p = pack[i * 64 + q];
    acc += __int_as_float(p.y) * h[(size_t)p.x * CH + t];
  }
  sp2[t] = acc * invdeg[i];
  __syncthreads();
  float a = bs[t] + bn[t] + 0.1f * cres[0] * sh[t];
  for (int k = 0; k < 64; k++) a += sh[k] * Ws[k * CH + t] + sp2[k] * Wn[k * CH + t];
  out[i * CH + t] = a / (1.0f + expf(-a));
}

__global__ __launch_bounds__(64) void pg_difffuse(
    const float* __restrict__ h2, const float* __restrict__ hd,
    const float* __restrict__ dW, const float* __restrict__ db, float* __restrict__ out)
{
  __shared__ float sh[3][64];
  int i = blockIdx.x, t = threadIdx.x;
  for (int s = 0; s < 3; s++) sh[s][t] = hd[(size_t)s * NPT * CH + i * CH + t];
  __syncthreads();
  float a = h2[i * CH + t] + db[t];
  for (int s = 0; s < 3; s++) {
    const float* w = dW + s * CH * CH;
    for (int k = 0; k < 64; k++) a += sh[s][k] * w[k * CH + t];
  }
  out[i * CH + t] = a;
}

__global__ __launch_bounds__(64) void pg_tlr(
    const int2* __restrict__ pack, const int* __restrict__ cnt,
    const float* __restrict__ Dis, const float* __restrict__ cvec,
    const float* __restrict__ h3,
    const float* __restrict__ W1, const float* __restrict__ b1,
    const float* __restrict__ W2, const float* __restrict__ b2,
    const float* __restrict__ rdc,
    const float* __restrict__ g, const float* __restrict__ b,
    float* __restrict__ hio)
{
  __shared__ float sh[64], st[64];
  int i = blockIdx.x, t = threadIdx.x;
  sh[t] = h3[i * CH + t];
  __syncthreads();
  float a = b1[t];
  for (int k = 0; k < 64; k++) a += sh[k] * W1[k * CH + t];
  st[t] = tanhf(a);
  int n = cnt[i];
  float accL = 0.0f;
  for (int q = 0; q < n; q++) {
    int2 p = pack[i * 64 + q];
    accL += __int_as_float(p.y) * Dis[p.x] * h3[(size_t)p.x * CH + t];
  }
  float tLv = accL * Dis[i] - cvec[i] * sh[t];
  __syncthreads();
  float react = b2[t];
  for (int k = 0; k < 64; k++) react += st[k] * W2[k * CH + t];
  float x = sh[t] + 0.1f * (rdc[t] * tLv + react) + hio[i * CH + t];
  float s = x;
  for (int off = 1; off < 64; off <<= 1) s += __shfl_xor(s, off);
  float mu = s * (1.0f / 64.0f);
  float d = x - mu;
  float v = d * d;
  for (int off = 1; off < 64; off <<= 1) v += __shfl_xor(v, off);
  v *= (1.0f / 64.0f);
  hio[i * CH + t] = d * (1.0f / sqrtf(v + 1e-5f)) * g[t] + b[t];
}

// ---------------------------------------------------------------- attention ---
__global__ __launch_bounds__(64) void pg_qkv(
    const float* __restrict__ h,
    const float* __restrict__ Wq, const float* __restrict__ bq,
    const float* __restrict__ Wk, const float* __restrict__ bk,
    const float* __restrict__ Wv, const float* __restrict__ bv,
    float* __restrict__ q, float* __restrict__ kb, float* __restrict__ vb)
{
  __shared__ float sh[64];
  int i = blockIdx.x, t = threadIdx.x;
  sh[t] = h[i * CH + t];
  __syncthreads();
  float aq = bq[t], ak = bk[t], avv = bv[t];
  for (int k = 0; k < 64; k++) {
    float x = sh[k];
    aq += x * Wq[k * CH + t];
    ak += x * Wk[k * CH + t];
    avv += x * Wv[k * CH + t];
  }
  q[i * CH + t] = aq;
  kb[i * CH + t] = ak;
  vb[i * CH + t] = avv;
}

__global__ __launch_bounds__(256) void pg_attn_out(
    const float* __restrict__ q, const float* __restrict__ kb, const float* __restrict__ vb,
    const int* __restrict__ nbr, const int* __restrict__ cnt,
    const float* __restrict__ Hc, const float* __restrict__ beta,
    const float* __restrict__ h,
    const float* __restrict__ Wo, const float* __restrict__ bo,
    const float* __restrict__ Wout, const float* __restrict__ bout,
    float* __restrict__ out)
{
  __shared__ float av_s[64];
  int i = blockIdx.x;
  int t = threadIdx.x;
  int head = t >> 6, lane = t & 63;
  float sp_b = logf(1.0f + expf(beta[head]));
  float hci = Hc[i];
  const float* qp = q + i * CH + head * 16;
  float qr[16];
#pragma unroll
  for (int d = 0; d < 16; d++) qr[d] = qp[d];
  int n = cnt[i];
  int K = n + 1;
  float mx = -1e30f, den = 0.0f;
  float vac[16];
#pragma unroll
  for (int d = 0; d < 16; d++) vac[d] = 0.0f;
  for (int m = lane; m < K; m += 64) {
    int j = (m == n) ? i : nbr[i * 64 + m];
    const float* kp = kb + (size_t)j * CH + head * 16;
    float sc = 0.0f;
#pragma unroll
    for (int d = 0; d < 16; d++) sc += qr[d] * kp[d];
    sc *= 0.25f;
    sc -= sp_b * fabsf(hci - Hc[j]);
    float nm = fmaxf(mx, sc);
    float corr = expf(mx - nm);
    float p = expf(sc - nm);
    den = den * corr + p;
    const float* vp = vb + (size_t)j * CH + head * 16;
#pragma unroll
    for (int d = 0; d < 16; d++) vac[d] = vac[d] * corr + p * vp[d];
    mx = nm;
  }
  for (int off = 32; off > 0; off >>= 1) {
    float omx = __shfl_down(mx, off);
    float oden = __shfl_down(den, off);
    float ov[16];
#pragma unroll
    for (int d = 0; d < 16; d++) ov[d] = __shfl_down(vac[d], off);
    float nm = fmaxf(mx, omx);
    float c1 = expf(mx - nm), c2 = expf(omx - nm);
    den = den * c1 + oden * c2;
#pragma unroll
    for (int d = 0; d < 16; d++) vac[d] = vac[d] * c1 + ov[d] * c2;
    mx = nm;
  }
  if (lane == 0) {
    float inv = 1.0f / den;
    for (int d = 0; d < 16; d++) av_s[head * 16 + d] = vac[d] * inv;
  }
  __syncthreads();
  if (t < 64) {
    float a = h[i * CH + t] + bo[t];
    for (int k = 0; k < 64; k++) a += av_s[k] * Wo[k * CH + t];
    float s = a * Wout[t];
    for (int off = 1; off < 64; off <<= 1) s += __shfl_xor(s, off);
    if (t == 0) out[i] = s + bout[0];
  }
}

// ------------------------------------------------------------------- launch ---
extern "C" void kernel_launch(void* const* d_in, const int* in_sizes, int n_in,
                              void* d_out, int out_size, void* d_ws, size_t ws_size,
                              hipStream_t stream)
{
  const float* pos   = (const float*)d_in[0];
  const float* adj   = (const float*)d_in[1];
  const float* Wc1   = (const float*)d_in[2];
  const float* bc1   = (const float*)d_in[3];
  const float* Wc2   = (const float*)d_in[4];
  const float* bc2   = (const float*)d_in[5];
  const float* Win   = (const float*)d_in[6];
  const float* b_in  = (const float*)d_in[7];
  const float* cWs   = (const float*)d_in[8];
  const float* cbs   = (const float*)d_in[9];
  const float* cWn   = (const float*)d_in[10];
  const float* cbn   = (const float*)d_in[11];
  const float* cres  = (const float*)d_in[12];
  const float* dW    = (const float*)d_in[13];
  const float* db    = (const float*)d_in[14];
  const float* rW1   = (const float*)d_in[15];
  const float* rb1   = (const float*)d_in[16];
  const float* rW2   = (const float*)d_in[17];
  const float* rb2   = (const float*)d_in[18];
  const float* rdc   = (const float*)d_in[19];
  const float* lng   = (const float*)d_in[20];
  const float* lnb   = (const float*)d_in[21];
  const float* Wq    = (const float*)d_in[22];
  const float* bq    = (const float*)d_in[23];
  const float* Wk    = (const float*)d_in[24];
  const float* bk    = (const float*)d_in[25];
  const float* Wv    = (const float*)d_in[26];
  const float* bv    = (const float*)d_in[27];
  const float* Wo    = (const float*)d_in[28];
  const float* bo    = (const float*)d_in[29];
  const float* abeta = (const float*)d_in[30];
  const float* Wout  = (const float*)d_in[31];
  const float* bout  = (const float*)d_in[32];

  const size_t NNe = (size_t)NPT * NPT;
  const size_t NC  = (size_t)NPT * CH;
  const size_t P   = NNe * 2;   // bytes per bf16 plane (8 MB)

  char* base = (char*)d_ws;
  bf16_t* E05h = (bf16_t*)(base + 0 * P);
  bf16_t* E05l = (bf16_t*)(base + 1 * P);
  bf16_t* E2h  = (bf16_t*)(base + 2 * P);
  bf16_t* E2l  = (bf16_t*)(base + 3 * P);
  bf16_t* E8h  = (bf16_t*)(base + 4 * P);
  bf16_t* E8l  = (bf16_t*)(base + 5 * P);
  bf16_t* SAh  = (bf16_t*)(base + 6 * P);
  bf16_t* SAl  = (bf16_t*)(base + 7 * P);
  bf16_t* SBh  = (bf16_t*)(base + 8 * P);
  bf16_t* SBl  = (bf16_t*)(base + 9 * P);
  // Horner ping-pong aliases planes 0-3 (dead before E05/E2 fixes write them)
  float*  M0   = (float*)(base + 0 * P);
  float*  M1   = (float*)(base + 2 * P);
  bf16_t* XTh  = (bf16_t*)(base + 12 * P);
  bf16_t* XTl  = (bf16_t*)(base + 12 * P + (size_t)NPT * CH * 2);
  bf16_t* XTh2 = (bf16_t*)(base + 12 * P + (size_t)NPT * CH * 4);
  float*  smb  = (float*)(base + 12 * P + 1024 * 1024);

  float* h   = smb;
  float* tA  = h + NC;
  float* tB  = tA + NC;
  float* hd  = tB + NC;        // 3*NC
  float* q   = hd + 3 * NC;
  float* kbf = q + NC;
  float* vbf = kbf + NC;
  float* raw = vbf + NC;
  float* sm  = raw + 8 * NPT;
  float* sumA   = sm;
  float* sumAD  = sm + NPT;
  float* wdeg   = sm + 2 * NPT;
  float* invdeg = sm + 3 * NPT;
  float* Dis    = sm + 4 * NPT;
  float* cvec   = sm + 5 * NPT;
  float* Hc     = sm + 6 * NPT;
  float* stats  = sm + 7 * NPT;
  int*   nbr    = (int*)(sm + 8 * NPT);
  int*   cnt    = nbr + (size_t)NPT * 64;
  int2*  pack   = (int2*)(cnt + NPT);

  size_t need = 12 * P + 1024 * 1024
              + (9 * NC + 16 * (size_t)NPT) * 4
              + (size_t)NPT * 64 * 4 + NPT * 4 + (size_t)NPT * 64 * 8 + 256;
  if (ws_size < need) return;

  // geometry + CSR + features
  pg_geom_csr<<<NPT, 256, 0, stream>>>(pos, adj, raw, Hc, sumA, sumAD, nbr, cnt);
  pg_stats<<<1, 256, 0, stream>>>(raw, sumA, sumAD, stats);
  pg_wdeg<<<NPT, 64, 0, stream>>>(pos, nbr, cnt, stats, pack, wdeg, invdeg, Dis, cvec);
  pg_curv_mlp<<<NPT, 64, 0, stream>>>(pos, raw, stats, Wc1, bc1, Wc2, bc2, Win, b_in, h);

  // T = exp(L/16): global ping-pong Taylor-Horner, XCD column stripes
  pg_hinit<<<NPT, 256, 0, stream>>>(pack, cnt, wdeg, M0);
  float* cur = M0;
  float* nxt = M1;
  for (int k = TDEG - 1; k >= 2; k--) {
    pg_hstep<false><<<NPT, 256, 0, stream>>>(pack, cnt, wdeg, cur, nxt,
                                             1.0f / (SCL * (float)k), nullptr, nullptr);
    float* tmp = cur; cur = nxt; nxt = tmp;
  }
  pg_hstep<true><<<NPT, 256, 0, stream>>>(pack, cnt, wdeg, cur, nullptr,
                                          1.0f / SCL, SAh, SAl);

  // squaring chain: 7 x 2-term squarings, fixes ONLY at consumed outputs.
  dim3 gfix(32, 16);
  pg_sq <<<512, 256, 0, stream>>>(SAh, SAl, SBh, SBl);     // U1 = L/8 (unfixed)
  pg_sq <<<512, 256, 0, stream>>>(SBh, SBl, SAh, SAl);     // U2 = L/4 (unfixed)
  pg_sq <<<512, 256, 0, stream>>>(SAh, SAl, SBh, SBl);     // U3 = L/2
  pg_fix<<<gfix, 256, 0, stream>>>(SBh, SBl, E05h, E05l);  // E05 = sym(U3)
  pg_sq <<<512, 256, 0, stream>>>(E05h, E05l, SAh, SAl);   // U4 = L (unfixed)
  pg_sq <<<512, 256, 0, stream>>>(SAh, SAl, SBh, SBl);     // U5 = 2L
  pg_fix<<<gfix, 256, 0, stream>>>(SBh, SBl, E2h, E2l);    // E2 = sym(U5)
  pg_sq <<<512, 256, 0, stream>>>(E2h, E2l, SAh, SAl);     // U6 = 4L (unfixed)
  pg_sq <<<512, 256, 0, stream>>>(SAh, SAl, SBh, SBl);     // U7 = 8L
  pg_fix<<<gfix, 256, 0, stream>>>(SBh, SBl, E8h, E8l);    // E8 = sym(U7)

  // NL layers
  for (int i = 0; i < 4; i++) {
    pg_convP<<<NPT, 64, 0, stream>>>(pack, cnt, invdeg, h,
                                     cWs + i * 4096, cbs + i * 64,
                                     cWn + i * 4096, cbn + i * 64, cres + i, tA);
    float* h3 = tA;
    if ((i & 1) == 0) {
      int j = i >> 1;
      pg_splitx<<<32, 256, 0, stream>>>(tA, XTh, XTl, XTh2);
      pg_emm<<<dim3(32, 3), 256, 0, stream>>>(E05h, E05l, E2h, E2l, E8h, E8l,
                                              XTh, XTl, XTh2, hd);
      pg_difffuse<<<NPT, 64, 0, stream>>>(tA, hd, dW + j * 3 * 4096, db + j * 64, tB);
      h3 = tB;
    }
    pg_tlr<<<NPT, 64, 0, stream>>>(pack, cnt, Dis, cvec, h3,
                                   rW1 + i * 4096, rb1 + i * 64,
                                   rW2 + i * 4096, rb2 + i * 64,
                                   rdc + i * 64, lng + i * 64, lnb + i * 64, h);
  }

  // attention + output
  pg_qkv<<<NPT, 64, 0, stream>>>(h, Wq, bq, Wk, bk, Wv, bv, q, kbf, vbf);
  pg_attn_out<<<NPT, 256, 0, stream>>>(q, kbf, vbf, nbr, cnt, Hc, abeta,
                                       h, Wo, bo, Wout, bout, (float*)d_out);
}